// Round 4
// baseline (269.598 us; speedup 1.0000x reference)
//
#include <hip/hip_runtime.h>
#include <hip/hip_bf16.h>
#include <cstdint>
#include <cstddef>

typedef __bf16 bf16x8 __attribute__((ext_vector_type(8)));
typedef float f32x4 __attribute__((ext_vector_type(4)));
typedef unsigned int uintx4 __attribute__((ext_vector_type(4)));

#define CONV_SCALE 0.014731391274719738f   // 1/sqrt(512*9)
#define MOD_SCALE  0.044194173824159216f   // 1/sqrt(512)

__device__ __forceinline__ unsigned short f2bf(float v) {
  unsigned int u = __float_as_uint(v);
  return (unsigned short)((u + 0x7FFFu + ((u >> 16) & 1u)) >> 16);  // RNE
}

__device__ __forceinline__ void gload16(const void* g, void* l) {
  __builtin_amdgcn_global_load_lds(
      (const __attribute__((address_space(1))) unsigned int*)g,
      (__attribute__((address_space(3))) unsigned int*)l, 16, 0, 0);
}

// s[b][ci] = dot(style[b], mod_w[ci]) * MOD_SCALE + mod_b[ci]
__global__ void k_modulate(const float* __restrict__ style,
                           const float* __restrict__ mod_w,
                           const float* __restrict__ mod_b,
                           float* __restrict__ s) {
  int blk = blockIdx.x;            // 32
  int b = blk >> 2, ch = blk & 3;
  int t = threadIdx.x;             // 256
  int ci = ch * 128 + (t >> 1), half = t & 1;
  const float* st = style + b * 512 + half * 256;
  const float* mw = mod_w + (size_t)ci * 512 + half * 256;
  float acc = 0.f;
  #pragma unroll 8
  for (int k = 0; k < 256; k += 4) {
    f32x4 a = *(const f32x4*)(st + k);
    f32x4 m = *(const f32x4*)(mw + k);
    acc += a[0] * m[0] + a[1] * m[1] + a[2] * m[2] + a[3] * m[3];
  }
  acc += __shfl_xor(acc, 1);
  if (half == 0) s[b * 512 + ci] = acc * MOD_SCALE + mod_b[ci];
}

// wT[tap][co][ci] = bf16(weight[co][ci][tap]);  wsq[co][ci] = cs^2 * sum_tap w^2
__global__ void k_wTq(const float* __restrict__ weight,
                      unsigned short* __restrict__ wT,
                      float* __restrict__ wsq) {
  __shared__ float lds[4608];
  int co = blockIdx.x;       // 512
  int t = threadIdx.x;       // 256
  const float* w = weight + (size_t)co * 4608;
  #pragma unroll
  for (int i = 0; i < 18; ++i) lds[t + i * 256] = w[t + i * 256];
  __syncthreads();
  for (int i = t; i < 576; i += 256) {
    int tap = i / 64, c8 = (i & 63) * 8;
    union { uintx4 v; unsigned short us[8]; } pk;
    #pragma unroll
    for (int j = 0; j < 8; ++j) pk.us[j] = f2bf(lds[(c8 + j) * 9 + tap]);
    *(uintx4*)(wT + ((size_t)tap * 512 + co) * 512 + c8) = pk.v;
  }
  for (int ci = t; ci < 512; ci += 256) {
    float a = 0.f;
    #pragma unroll
    for (int tap = 0; tap < 9; ++tap) { float v = lds[ci * 9 + tap]; a += v * v; }
    wsq[co * 512 + ci] = a * (CONV_SCALE * CONV_SCALE);
  }
}

// demod[b][co] = rsqrt( sum_ci wsq[co][ci]*s[b][ci]^2 + 1e-8 )
__global__ void k_demod(const float* __restrict__ wsq, const float* __restrict__ s,
                        float* __restrict__ demod) {
  int b = blockIdx.x;        // 8
  int co = threadIdx.x;      // 512
  const float* wq = wsq + (size_t)co * 512;
  const float* sb = s + b * 512;
  float acc = 0.f;
  #pragma unroll 4
  for (int ci = 0; ci < 512; ci += 4) {
    f32x4 q = *(const f32x4*)(wq + ci);
    f32x4 v = *(const f32x4*)(sb + ci);
    acc += q[0] * v[0] * v[0] + q[1] * v[1] * v[1] + q[2] * v[2] * v[2] + q[3] * v[3] * v[3];
  }
  demod[b * 512 + co] = rsqrtf(acc + 1e-8f);
}

// xT[b][h][w][ci] = bf16( x[b][ci][h][w] * s[b][ci] )   (transpose to ci-contiguous)
__global__ void k_xT(const float* __restrict__ x, const float* __restrict__ s,
                     unsigned short* __restrict__ xT) {
  __shared__ float lds[128][68];
  int cc = blockIdx.x;       // ci chunk of 128 (4 chunks)
  int h = blockIdx.y;        // 64
  int b = blockIdx.z;        // 8
  int t = threadIdx.x;       // 256
  int w4 = (t & 15) * 4, rr = t >> 4;
  #pragma unroll
  for (int i = 0; i < 8; ++i) {
    int ci = i * 16 + rr;
    *(f32x4*)&lds[ci][w4] =
        *(const f32x4*)&x[(((size_t)(b * 512 + cc * 128 + ci)) * 64 + h) * 64 + w4];
  }
  __syncthreads();
  int pos = t >> 2, c4 = t & 3;
  #pragma unroll
  for (int q = 0; q < 4; ++q) {
    int cb = q * 32 + c4 * 8;
    union { uintx4 v; unsigned short us[8]; } pk;
    #pragma unroll
    for (int j = 0; j < 8; ++j) {
      int ci = cb + j;
      pk.us[j] = f2bf(lds[ci][pos] * s[b * 512 + cc * 128 + ci]);
    }
    *(uintx4*)(xT + (((size_t)(b * 64 + h)) * 64 + pos) * 512 + cc * 128 + cb) = pk.v;
  }
}

// Implicit-GEMM conv, pipelined. Block: 512 thr / 8 waves, tile 64co x 16 rows x 64 w
// (2 rows per wave). K-loop: 16 chunks of 32 ci, inner 9 taps, MFMA 16x16x32 bf16.
// Pipeline per chunk cc: issue x-loads(cc+1)->regs + w gload_lds(cc+1)->wbuf^1,
// compute 9 taps from xlds/wbuf, barrier (implicit vmcnt drain lands HERE, hidden
// under ~5600cyc of taps), ds_write x regs (swizzled), barrier.
// LDS: x halo 18*66*64B = 76032 + w dbuf 2*576*64B = 73728 -> 149760 B (1 block/CU).
__global__ __launch_bounds__(512, 2) void k_conv(
    const unsigned short* __restrict__ xT,   // [B][64][64][512]
    const unsigned short* __restrict__ wT,   // [9][512][512]
    const float* __restrict__ demod,         // [B][512]
    float* __restrict__ out) {               // [B][512][64][64]
  extern __shared__ __align__(16) char lds_raw[];
  char* xlds = lds_raw;            // 18 rows * 66 pos * 64B = 76032
  char* wlds = lds_raw + 76032;    // 2 * (576 rows * 64B) = 73728

  const int co_t = blockIdx.x;    // 8
  const int h_t  = blockIdx.y;    // 4
  const int b    = blockIdx.z;    // 8
  const int t = threadIdx.x;      // 512
  const int lane = t & 63, wv = t >> 6;
  const int h0 = h_t * 16;
  const int co0 = co_t * 64;
  const int l15 = lane & 15, kg = lane >> 4;

  // zero whole x tile once (covers halo cols 0/65 and OOB rows forever)
  {
    uintx4 z = {0u, 0u, 0u, 0u};
    for (int i = t; i < 4752; i += 512) ((uintx4*)xlds)[i] = z;
  }

  // ---- x reg-staging geometry: thread covers slot(t&3) of col (t>>2)&63, rows 2k+(t>>8)
  const int slot = t & 3;
  const int c    = (t >> 2) & 63;
  const int rb   = t >> 8;                 // 0/1, wave-uniform
  unsigned xgo[9]; unsigned xlo[9]; bool xv[9];
  #pragma unroll
  for (int k = 0; k < 9; ++k) {
    int r = 2 * k + rb;
    int hh = h0 - 1 + r;
    xv[k] = ((unsigned)hh < 64u);
    int p = r * 66 + 1 + c;
    xlo[k] = p * 64 + ((slot ^ ((p >> 1) & 3)) << 4);
    xgo[k] = ((unsigned)((b * 64 + (xv[k] ? hh : 0)) * 64 + c) << 10) + slot * 16;
  }
  const char* xTb = (const char*)xT;
  uintx4 xr[9] = {};

  auto xissue = [&](int ccn) {
    unsigned off = ccn * 64;
    #pragma unroll
    for (int k = 0; k < 9; ++k)
      if (xv[k]) xr[k] = *(const uintx4*)(xTb + xgo[k] + off);
  };
  auto xwrite = [&]() {
    #pragma unroll
    for (int k = 0; k < 9; ++k) *(uintx4*)(xlds + xlo[k]) = xr[k];
  };
  // ---- w staging via global_load_lds, pre-swizzled source, linear dest
  auto wissue = [&](int ccn, char* wb) {
    for (int j = wv; j < 36; j += 8) {
      int row0 = j * 16;
      int row = row0 + (lane >> 2);
      int tap = row >> 6, co = row & 63;
      const unsigned short* g = wT + ((size_t)tap * 512 + co0 + co) * 512
                                + ccn * 32 + (((lane & 3) ^ ((row >> 1) & 3)) << 3);
      gload16(g, wb + row0 * 64);
    }
  };

  f32x4 acc[4][2][4] = {};        // [m(co)][r(row)][n(w)]

  char* wb0 = wlds;
  char* wb1 = wlds + 36864;

  // prologue: stage chunk 0
  xissue(0);
  wissue(0, wb0);
  xwrite();
  __syncthreads();

  #pragma unroll 1
  for (int cc = 0; cc < 16; ++cc) {
    char* wb = (cc & 1) ? wb1 : wb0;
    if (cc < 15) {
      xissue(cc + 1);
      wissue(cc + 1, (cc & 1) ? wb0 : wb1);
      __builtin_amdgcn_sched_barrier(0);   // keep issue cluster above the MFMAs
    }
    __builtin_amdgcn_s_setprio(1);
    #pragma unroll
    for (int tap = 0; tap < 9; ++tap) {
      const int dh = tap / 3, dw = tap % 3;
      bf16x8 af[4], bfr[2][4];
      #pragma unroll
      for (int m = 0; m < 4; ++m) {
        int row = tap * 64 + m * 16 + l15;
        af[m] = *(const bf16x8*)(wb + row * 64 + ((kg ^ ((row >> 1) & 3)) << 4));
      }
      #pragma unroll
      for (int r = 0; r < 2; ++r)
        #pragma unroll
        for (int n = 0; n < 4; ++n) {
          int p = (2 * wv + r + dh) * 66 + n * 16 + l15 + dw;
          bfr[r][n] = *(const bf16x8*)(xlds + p * 64 + ((kg ^ ((p >> 1) & 3)) << 4));
        }
      #pragma unroll
      for (int m = 0; m < 4; ++m)
        #pragma unroll
        for (int r = 0; r < 2; ++r)
          #pragma unroll
          for (int n = 0; n < 4; ++n)
            acc[m][r][n] = __builtin_amdgcn_mfma_f32_16x16x32_bf16(af[m], bfr[r][n], acc[m][r][n], 0, 0, 0);
    }
    __builtin_amdgcn_s_setprio(0);
    if (cc < 15) {
      __syncthreads();                     // all reads done + vmcnt drained (hidden)
      xwrite();
      __syncthreads();                     // x tile ready for next chunk
    }
  }

  // epilogue: out[b][co][h0+2*wv+r][w] = acc * conv_scale * demod[b][co]
  #pragma unroll
  for (int m = 0; m < 4; ++m) {
    #pragma unroll
    for (int q = 0; q < 4; ++q) {
      int co = co0 + m * 16 + kg * 4 + q;
      float scl = CONV_SCALE * demod[b * 512 + co];
      #pragma unroll
      for (int r = 0; r < 2; ++r) {
        int h_out = h0 + 2 * wv + r;
        #pragma unroll
        for (int n = 0; n < 4; ++n) {
          out[(((size_t)(b * 512 + co)) * 64 + h_out) * 64 + n * 16 + l15] = acc[m][r][n][q] * scl;
        }
      }
    }
  }
}

extern "C" void kernel_launch(void* const* d_in, const int* in_sizes, int n_in,
                              void* d_out, int out_size, void* d_ws, size_t ws_size,
                              hipStream_t stream) {
  const float* x      = (const float*)d_in[0];  // (8,512,64,64)
  const float* style  = (const float*)d_in[1];  // (8,512)
  const float* weight = (const float*)d_in[2];  // (1,512,512,3,3)
  const float* mod_w  = (const float*)d_in[3];  // (512,512)
  const float* mod_b  = (const float*)d_in[4];  // (512,)
  float* out = (float*)d_out;

  // workspace layout (~39.4 MB)
  char* ws = (char*)d_ws;
  unsigned short* xT = (unsigned short*)ws;               // 33,554,432 B
  unsigned short* wT = (unsigned short*)(ws + 33554432);  //  4,718,592 B
  float* s     = (float*)(ws + 38273024);                 //     16,384 B
  float* wsq   = (float*)(ws + 38289408);                 //  1,048,576 B
  float* demod = (float*)(ws + 39337984);                 //     16,384 B

  static int lds_set = 0;
  if (!lds_set) {
    (void)hipFuncSetAttribute((const void*)k_conv,
                              hipFuncAttributeMaxDynamicSharedMemorySize, 149760);
    lds_set = 1;
  }

  hipLaunchKernelGGL(k_modulate, dim3(32),       dim3(256), 0, stream, style, mod_w, mod_b, s);
  hipLaunchKernelGGL(k_wTq,      dim3(512),      dim3(256), 0, stream, weight, wT, wsq);
  hipLaunchKernelGGL(k_demod,    dim3(8),        dim3(512), 0, stream, wsq, s, demod);
  hipLaunchKernelGGL(k_xT,       dim3(4, 64, 8), dim3(256), 0, stream, x, s, xT);
  hipLaunchKernelGGL(k_conv,     dim3(8, 4, 8),  dim3(512), 149760, stream, xT, wT, demod, out);
}

// Round 5
// 189.438 us; speedup vs baseline: 1.4231x; 1.4231x over previous
//
#include <hip/hip_runtime.h>
#include <hip/hip_bf16.h>
#include <cstdint>
#include <cstddef>

typedef __bf16 bf16x8 __attribute__((ext_vector_type(8)));
typedef float f32x4 __attribute__((ext_vector_type(4)));
typedef unsigned int uintx4 __attribute__((ext_vector_type(4)));

#define CONV_SCALE 0.014731391274719738f   // 1/sqrt(512*9)
#define MOD_SCALE  0.044194173824159216f   // 1/sqrt(512)

__device__ __forceinline__ unsigned short f2bf(float v) {
  unsigned int u = __float_as_uint(v);
  return (unsigned short)((u + 0x7FFFu + ((u >> 16) & 1u)) >> 16);  // RNE
}

__device__ __forceinline__ void gload16(const void* g, void* l) {
  __builtin_amdgcn_global_load_lds(
      (const __attribute__((address_space(1))) unsigned int*)g,
      (__attribute__((address_space(3))) unsigned int*)l, 16, 0, 0);
}

// s[b][ci] = dot(style[b], mod_w[ci]) * MOD_SCALE + mod_b[ci]
__global__ void k_modulate(const float* __restrict__ style,
                           const float* __restrict__ mod_w,
                           const float* __restrict__ mod_b,
                           float* __restrict__ s) {
  int blk = blockIdx.x;            // 32
  int b = blk >> 2, ch = blk & 3;
  int t = threadIdx.x;             // 256
  int ci = ch * 128 + (t >> 1), half = t & 1;
  const float* st = style + b * 512 + half * 256;
  const float* mw = mod_w + (size_t)ci * 512 + half * 256;
  float acc = 0.f;
  #pragma unroll 8
  for (int k = 0; k < 256; k += 4) {
    f32x4 a = *(const f32x4*)(st + k);
    f32x4 m = *(const f32x4*)(mw + k);
    acc += a[0] * m[0] + a[1] * m[1] + a[2] * m[2] + a[3] * m[3];
  }
  acc += __shfl_xor(acc, 1);
  if (half == 0) s[b * 512 + ci] = acc * MOD_SCALE + mod_b[ci];
}

// wT[tap][co][ci] = bf16(weight[co][ci][tap]);  wsq[co][ci] = cs^2 * sum_tap w^2
__global__ void k_wTq(const float* __restrict__ weight,
                      unsigned short* __restrict__ wT,
                      float* __restrict__ wsq) {
  __shared__ float lds[4608];
  int co = blockIdx.x;       // 512
  int t = threadIdx.x;       // 256
  const float* w = weight + (size_t)co * 4608;
  #pragma unroll
  for (int i = 0; i < 18; ++i) lds[t + i * 256] = w[t + i * 256];
  __syncthreads();
  for (int i = t; i < 576; i += 256) {
    int tap = i / 64, c8 = (i & 63) * 8;
    union { uintx4 v; unsigned short us[8]; } pk;
    #pragma unroll
    for (int j = 0; j < 8; ++j) pk.us[j] = f2bf(lds[(c8 + j) * 9 + tap]);
    *(uintx4*)(wT + ((size_t)tap * 512 + co) * 512 + c8) = pk.v;
  }
  for (int ci = t; ci < 512; ci += 256) {
    float a = 0.f;
    #pragma unroll
    for (int tap = 0; tap < 9; ++tap) { float v = lds[ci * 9 + tap]; a += v * v; }
    wsq[co * 512 + ci] = a * (CONV_SCALE * CONV_SCALE);
  }
}

// demod[b][co] = rsqrt( sum_ci wsq[co][ci]*s[b][ci]^2 + 1e-8 )
__global__ void k_demod(const float* __restrict__ wsq, const float* __restrict__ s,
                        float* __restrict__ demod) {
  int b = blockIdx.x;        // 8
  int co = threadIdx.x;      // 512
  const float* wq = wsq + (size_t)co * 512;
  const float* sb = s + b * 512;
  float acc = 0.f;
  #pragma unroll 4
  for (int ci = 0; ci < 512; ci += 4) {
    f32x4 q = *(const f32x4*)(wq + ci);
    f32x4 v = *(const f32x4*)(sb + ci);
    acc += q[0] * v[0] * v[0] + q[1] * v[1] * v[1] + q[2] * v[2] * v[2] + q[3] * v[3] * v[3];
  }
  demod[b * 512 + co] = rsqrtf(acc + 1e-8f);
}

// xT[b][h][w][ci] = bf16( x[b][ci][h][w] * s[b][ci] )   (transpose to ci-contiguous)
__global__ void k_xT(const float* __restrict__ x, const float* __restrict__ s,
                     unsigned short* __restrict__ xT) {
  __shared__ float lds[128][68];
  int cc = blockIdx.x;       // ci chunk of 128 (4 chunks)
  int h = blockIdx.y;        // 64
  int b = blockIdx.z;        // 8
  int t = threadIdx.x;       // 256
  int w4 = (t & 15) * 4, rr = t >> 4;
  #pragma unroll
  for (int i = 0; i < 8; ++i) {
    int ci = i * 16 + rr;
    *(f32x4*)&lds[ci][w4] =
        *(const f32x4*)&x[(((size_t)(b * 512 + cc * 128 + ci)) * 64 + h) * 64 + w4];
  }
  __syncthreads();
  int pos = t >> 2, c4 = t & 3;
  #pragma unroll
  for (int q = 0; q < 4; ++q) {
    int cb = q * 32 + c4 * 8;
    union { uintx4 v; unsigned short us[8]; } pk;
    #pragma unroll
    for (int j = 0; j < 8; ++j) {
      int ci = cb + j;
      pk.us[j] = f2bf(lds[ci][pos] * s[b * 512 + cc * 128 + ci]);
    }
    *(uintx4*)(xT + (((size_t)(b * 64 + h)) * 64 + pos) * 512 + cc * 128 + cb) = pk.v;
  }
}

// Implicit-GEMM conv (R3 structure: 2 blocks/CU, gload_lds staging, 2-barrier loop).
// Block tile: 64 Cout x (8 rows x 64 cols), 4 waves (2 rows each).
// XCD-locality swizzle: 1D grid of 512; id&7 = XCD (HW round-robin); within an
// XCD, co_t varies fastest across 8 (b,h_t) slices -> x-slice and w tile are
// L2-resident per XCD (per-chunk working set ~620 KB << 4 MB).
__global__ __launch_bounds__(256, 2) void k_conv(
    const unsigned short* __restrict__ xT,   // [B][64][64][512]
    const unsigned short* __restrict__ wT,   // [9][512][512]
    const float* __restrict__ demod,         // [B][512]
    float* __restrict__ out) {               // [B][512][64][64]
  extern __shared__ __align__(16) char lds_raw[];
  char* xlds = lds_raw;            // 660 positions (10*66) * 64B = 42240
  char* wlds = lds_raw + 42240;    // 576 rows (9 taps * 64 co) * 64B = 36864

  // swizzled decomposition
  const int id  = blockIdx.x;      // 512
  const int xcd = id & 7;
  const int li  = id >> 3;         // 0..63 within XCD
  const int slice = xcd * 8 + (li >> 3);  // 0..63
  const int co_t = li & 7;
  const int b    = slice >> 3;
  const int h_t  = slice & 7;

  const int t = threadIdx.x;
  const int lane = t & 63, wv = t >> 6;
  const int h0 = h_t * 8;
  const int co0 = co_t * 64;
  const int l15 = lane & 15, kg = lane >> 4;

  // zero whole x tile once (covers halo cols 0/65 and OOB rows forever)
  {
    uintx4 z = {0u, 0u, 0u, 0u};
    for (int i = t; i < 2640; i += 256) ((uintx4*)xlds)[i] = z;
  }

  f32x4 acc[4][2][4] = {};        // [m(co)][r(row)][n(w)]

  for (int cc = 0; cc < 16; ++cc) {
    __syncthreads();
    // stage x interior: 10 rows x 4 chunks of 16 positions (1KB per issue)
    for (int j = wv; j < 40; j += 4) {
      int r = j >> 2, k = j & 3;
      int hh = h0 - 1 + r;
      if ((unsigned)hh < 64u) {
        int p0 = r * 66 + 1 + k * 16;
        int p = p0 + (lane >> 2);
        const unsigned short* g = xT + (((size_t)(b * 64 + hh)) * 64 + k * 16 + (lane >> 2)) * 512
                                  + cc * 32 + (((lane & 3) ^ ((p >> 1) & 3)) << 3);
        gload16(g, xlds + p0 * 64);
      }
    }
    // stage weights: 36 chunks of 16 rows
    for (int j = wv; j < 36; j += 4) {
      int row0 = j * 16;
      int row = row0 + (lane >> 2);
      int tap = row >> 6, co = row & 63;
      const unsigned short* g = wT + ((size_t)tap * 512 + co0 + co) * 512
                                + cc * 32 + (((lane & 3) ^ ((row >> 1) & 3)) << 3);
      gload16(g, wlds + row0 * 64);
    }
    __syncthreads();

    #pragma unroll
    for (int tap = 0; tap < 9; ++tap) {
      const int dh = tap / 3, dw = tap % 3;
      bf16x8 af[4], bfr[2][4];
      #pragma unroll
      for (int m = 0; m < 4; ++m) {
        int row = tap * 64 + m * 16 + l15;
        af[m] = *(const bf16x8*)(wlds + row * 64 + ((kg ^ ((row >> 1) & 3)) << 4));
      }
      #pragma unroll
      for (int r = 0; r < 2; ++r)
        #pragma unroll
        for (int n = 0; n < 4; ++n) {
          int p = (2 * wv + r + dh) * 66 + n * 16 + l15 + dw;
          bfr[r][n] = *(const bf16x8*)(xlds + p * 64 + ((kg ^ ((p >> 1) & 3)) << 4));
        }
      #pragma unroll
      for (int m = 0; m < 4; ++m)
        #pragma unroll
        for (int r = 0; r < 2; ++r)
          #pragma unroll
          for (int n = 0; n < 4; ++n)
            acc[m][r][n] = __builtin_amdgcn_mfma_f32_16x16x32_bf16(af[m], bfr[r][n], acc[m][r][n], 0, 0, 0);
    }
  }

  // epilogue: out[b][co][h0+2*wv+r][w] = acc * conv_scale * demod[b][co]
  #pragma unroll
  for (int m = 0; m < 4; ++m) {
    #pragma unroll
    for (int q = 0; q < 4; ++q) {
      int co = co0 + m * 16 + kg * 4 + q;
      float scl = CONV_SCALE * demod[b * 512 + co];
      #pragma unroll
      for (int r = 0; r < 2; ++r) {
        int h_out = h0 + 2 * wv + r;
        #pragma unroll
        for (int n = 0; n < 4; ++n) {
          out[(((size_t)(b * 512 + co)) * 64 + h_out) * 64 + n * 16 + l15] = acc[m][r][n][q] * scl;
        }
      }
    }
  }
}

extern "C" void kernel_launch(void* const* d_in, const int* in_sizes, int n_in,
                              void* d_out, int out_size, void* d_ws, size_t ws_size,
                              hipStream_t stream) {
  const float* x      = (const float*)d_in[0];  // (8,512,64,64)
  const float* style  = (const float*)d_in[1];  // (8,512)
  const float* weight = (const float*)d_in[2];  // (1,512,512,3,3)
  const float* mod_w  = (const float*)d_in[3];  // (512,512)
  const float* mod_b  = (const float*)d_in[4];  // (512,)
  float* out = (float*)d_out;

  // workspace layout (~39.4 MB)
  char* ws = (char*)d_ws;
  unsigned short* xT = (unsigned short*)ws;               // 33,554,432 B
  unsigned short* wT = (unsigned short*)(ws + 33554432);  //  4,718,592 B
  float* s     = (float*)(ws + 38273024);                 //     16,384 B
  float* wsq   = (float*)(ws + 38289408);                 //  1,048,576 B
  float* demod = (float*)(ws + 39337984);                 //     16,384 B

  static int lds_set = 0;
  if (!lds_set) {
    (void)hipFuncSetAttribute((const void*)k_conv,
                              hipFuncAttributeMaxDynamicSharedMemorySize, 79104);
    lds_set = 1;
  }

  hipLaunchKernelGGL(k_modulate, dim3(32),       dim3(256), 0, stream, style, mod_w, mod_b, s);
  hipLaunchKernelGGL(k_wTq,      dim3(512),      dim3(256), 0, stream, weight, wT, wsq);
  hipLaunchKernelGGL(k_demod,    dim3(8),        dim3(512), 0, stream, wsq, s, demod);
  hipLaunchKernelGGL(k_xT,       dim3(4, 64, 8), dim3(256), 0, stream, x, s, xT);
  hipLaunchKernelGGL(k_conv,     dim3(512),      dim3(256), 79104, stream, xT, wT, demod, out);
}

// Round 6
// 183.158 us; speedup vs baseline: 1.4719x; 1.0343x over previous
//
#include <hip/hip_runtime.h>
#include <hip/hip_bf16.h>
#include <cstdint>
#include <cstddef>

typedef __bf16 bf16x8 __attribute__((ext_vector_type(8)));
typedef float f32x4 __attribute__((ext_vector_type(4)));
typedef unsigned int uintx4 __attribute__((ext_vector_type(4)));

#define CONV_SCALE 0.014731391274719738f   // 1/sqrt(512*9)
#define MOD_SCALE  0.044194173824159216f   // 1/sqrt(512)

__device__ __forceinline__ unsigned short f2bf(float v) {
  unsigned int u = __float_as_uint(v);
  return (unsigned short)((u + 0x7FFFu + ((u >> 16) & 1u)) >> 16);  // RNE
}

__device__ __forceinline__ void gload16(const void* g, void* l) {
  __builtin_amdgcn_global_load_lds(
      (const __attribute__((address_space(1))) unsigned int*)g,
      (__attribute__((address_space(3))) unsigned int*)l, 16, 0, 0);
}

// s[b][ci] = dot(style[b], mod_w[ci]) * MOD_SCALE + mod_b[ci]
__global__ void k_modulate(const float* __restrict__ style,
                           const float* __restrict__ mod_w,
                           const float* __restrict__ mod_b,
                           float* __restrict__ s) {
  int blk = blockIdx.x;            // 32
  int b = blk >> 2, ch = blk & 3;
  int t = threadIdx.x;             // 256
  int ci = ch * 128 + (t >> 1), half = t & 1;
  const float* st = style + b * 512 + half * 256;
  const float* mw = mod_w + (size_t)ci * 512 + half * 256;
  float acc = 0.f;
  #pragma unroll 8
  for (int k = 0; k < 256; k += 4) {
    f32x4 a = *(const f32x4*)(st + k);
    f32x4 m = *(const f32x4*)(mw + k);
    acc += a[0] * m[0] + a[1] * m[1] + a[2] * m[2] + a[3] * m[3];
  }
  acc += __shfl_xor(acc, 1);
  if (half == 0) s[b * 512 + ci] = acc * MOD_SCALE + mod_b[ci];
}

// wT[tap][co][ci] = bf16(weight[co][ci][tap]);  wsq[co][ci] = cs^2 * sum_tap w^2
__global__ void k_wTq(const float* __restrict__ weight,
                      unsigned short* __restrict__ wT,
                      float* __restrict__ wsq) {
  __shared__ float lds[4608];
  int co = blockIdx.x;       // 512
  int t = threadIdx.x;       // 256
  const float* w = weight + (size_t)co * 4608;
  #pragma unroll
  for (int i = 0; i < 18; ++i) lds[t + i * 256] = w[t + i * 256];
  __syncthreads();
  for (int i = t; i < 576; i += 256) {
    int tap = i / 64, c8 = (i & 63) * 8;
    union { uintx4 v; unsigned short us[8]; } pk;
    #pragma unroll
    for (int j = 0; j < 8; ++j) pk.us[j] = f2bf(lds[(c8 + j) * 9 + tap]);
    *(uintx4*)(wT + ((size_t)tap * 512 + co) * 512 + c8) = pk.v;
  }
  for (int ci = t; ci < 512; ci += 256) {
    float a = 0.f;
    #pragma unroll
    for (int tap = 0; tap < 9; ++tap) { float v = lds[ci * 9 + tap]; a += v * v; }
    wsq[co * 512 + ci] = a * (CONV_SCALE * CONV_SCALE);
  }
}

// demod[b][co] = rsqrt( sum_ci wsq[co][ci]*s[b][ci]^2 + 1e-8 )
__global__ void k_demod(const float* __restrict__ wsq, const float* __restrict__ s,
                        float* __restrict__ demod) {
  int b = blockIdx.x;        // 8
  int co = threadIdx.x;      // 512
  const float* wq = wsq + (size_t)co * 512;
  const float* sb = s + b * 512;
  float acc = 0.f;
  #pragma unroll 4
  for (int ci = 0; ci < 512; ci += 4) {
    f32x4 q = *(const f32x4*)(wq + ci);
    f32x4 v = *(const f32x4*)(sb + ci);
    acc += q[0] * v[0] * v[0] + q[1] * v[1] * v[1] + q[2] * v[2] * v[2] + q[3] * v[3] * v[3];
  }
  demod[b * 512 + co] = rsqrtf(acc + 1e-8f);
}

// xT[b][h][w][ci] = bf16( x[b][ci][h][w] * s[b][ci] )   (transpose to ci-contiguous)
__global__ void k_xT(const float* __restrict__ x, const float* __restrict__ s,
                     unsigned short* __restrict__ xT) {
  __shared__ float lds[128][68];
  int cc = blockIdx.x;       // ci chunk of 128 (4 chunks)
  int h = blockIdx.y;        // 64
  int b = blockIdx.z;        // 8
  int t = threadIdx.x;       // 256
  int w4 = (t & 15) * 4, rr = t >> 4;
  #pragma unroll
  for (int i = 0; i < 8; ++i) {
    int ci = i * 16 + rr;
    *(f32x4*)&lds[ci][w4] =
        *(const f32x4*)&x[(((size_t)(b * 512 + cc * 128 + ci)) * 64 + h) * 64 + w4];
  }
  __syncthreads();
  int pos = t >> 2, c4 = t & 3;
  #pragma unroll
  for (int q = 0; q < 4; ++q) {
    int cb = q * 32 + c4 * 8;
    union { uintx4 v; unsigned short us[8]; } pk;
    #pragma unroll
    for (int j = 0; j < 8; ++j) {
      int ci = cb + j;
      pk.us[j] = f2bf(lds[ci][pos] * s[b * 512 + cc * 128 + ci]);
    }
    *(uintx4*)(xT + (((size_t)(b * 64 + h)) * 64 + pos) * 512 + cc * 128 + cb) = pk.v;
  }
}

// Implicit-GEMM conv, m201-style phase pipeline.
// 256 blocks (1/CU), 512 thr / 8 waves. Tile: 128co x 8rows x 64w; wave: 64co x 2rows.
// LDS: x dbuf 2*42240 + w 4-slot tap-ring 4*8192 + trash 1024 = 118272 B.
// Per tap-phase g: vmcnt(N) -> ds_read 12 frags (slot g&3 staged at g-2; x[cur]) ->
// issue gload_lds {w for g+2 (1/wave), x for next chunk at taps 1..5 (1/wave)} ->
// raw s_barrier -> setprio(1) 32 MFMA setprio(0).  Loads NEVER drain in main loop;
// uniform per-wave issue counts make per-phase vmcnt constants exact:
// N(tap) = issues(prev tap) = {1,1,2,2,2,2,2,1,1}.
// Safety: ring distance 2 + barrier-bounded drift <=1 phase; invalid/past-end
// stages redirect to trash slot (keeps vmcnt accounting uniform).
__global__ __launch_bounds__(512, 2) void k_conv(
    const unsigned short* __restrict__ xT,   // [B][64][64][512]
    const unsigned short* __restrict__ wT,   // [9][512][512]
    const float* __restrict__ demod,         // [B][512]
    float* __restrict__ out) {               // [B][512][64][64]
  extern __shared__ __align__(16) char lds_raw[];
  char* xb0   = lds_raw;              // 42240
  char* xb1   = lds_raw + 42240;      // 42240
  char* wring = lds_raw + 84480;      // 4 * 8192
  char* trash = lds_raw + 117248;     // 1024

  const int id  = blockIdx.x;         // 256
  const int g_ord = (id & 7) * 32 + (id >> 3);   // XCD-contiguous ordering
  const int co_t  = g_ord >> 6;       // 0..3
  const int slice = g_ord & 63;       // 0..63
  const int b   = slice >> 3;
  const int h_t = slice & 7;

  const int t = threadIdx.x;          // 512
  const int lane = t & 63, wv = t >> 6;   // 8 waves
  const int h0  = h_t * 8;
  const int co0 = co_t * 128;
  const int l15 = lane & 15, kg = lane >> 4;
  const int wrow = wv & 3;            // row-pair within tile
  const int wco  = wv >> 2;           // co half (0/1)

  // zero both x buffers (halo cols 0/65 + OOB rows stay zero forever)
  {
    uintx4 z = {0u, 0u, 0u, 0u};
    for (int i = t; i < 5280; i += 512) ((uintx4*)lds_raw)[i] = z;
  }
  __syncthreads();

  // ---- x stage: issue j in 0..39 (j = r*4 + k), 1 KB per wave-issue
  auto xstage = [&](int j, int ccs, char* xbuf) {
    int r = j >> 2, k = j & 3;
    int hh = h0 - 1 + r;
    int hc = ((unsigned)hh < 64u) ? hh : 0;
    int p = r * 66 + 1 + k * 16 + (lane >> 2);
    const void* src = xT + (((size_t)(b * 64 + hc)) * 64 + k * 16 + (lane >> 2)) * 512
                      + ccs * 32 + (((lane & 3) ^ ((p >> 1) & 3)) << 3);
    void* dst = ((unsigned)hh < 64u) ? (void*)(xbuf + (r * 66 + 1 + k * 16) * 64)
                                     : (void*)trash;
    gload16(src, dst);
  };
  // ---- w stage for global tap g (slot g&3): 1 KB per wave-issue (16 rows)
  auto wstage = [&](int g) {
    int gc = (g <= 143) ? g : 143;
    int s = g & 3;
    int cc2 = gc / 9, tap2 = gc - cc2 * 9;
    int row0 = wv * 16;
    int row = row0 + (lane >> 2);
    const void* src = wT + ((size_t)tap2 * 512 + co0 + row) * 512
                      + cc2 * 32 + (((lane & 3) ^ ((row >> 1) & 3)) << 3);
    void* dst = (g <= 143) ? (void*)(wring + s * 8192 + row0 * 64) : (void*)trash;
    gload16(src, dst);
  };

  f32x4 acc[4][2][4] = {};            // [m(co)][r(row)][n(w)]

  // prologue: x[0] fully (5/wave), w slots g=0,1 (1/wave each); drain once.
  #pragma unroll
  for (int i = 0; i < 5; ++i) xstage(wv * 5 + i, 0, xb0);
  wstage(0);
  wstage(1);
  __syncthreads();                    // full drain (once)

  #pragma unroll 1
  for (int cc = 0; cc < 16; ++cc) {
    const char* xcur = (cc & 1) ? xb1 : xb0;
    char* xnxt = (cc & 1) ? xb0 : xb1;
    const int ccs = (cc + 1) & 15;    // wrapped src chunk for next-x (cc=15: dummy)
    #pragma unroll
    for (int tap = 0; tap < 9; ++tap) {
      // 1. counted vmcnt: N = issues(prev phase) = {1,1,2,2,2,2,2,1,1}
      if (tap == 0 || tap == 1 || tap == 7 || tap == 8)
        asm volatile("s_waitcnt vmcnt(1)" ::: "memory");
      else
        asm volatile("s_waitcnt vmcnt(2)" ::: "memory");

      const int g = cc * 9 + tap;
      const int s = g & 3;
      const int dh = tap / 3, dw = tap % 3;

      // 2. ds_read this tap's fragments (w slot staged at g-2; x[cur])
      bf16x8 af[4], bfr[2][4];
      #pragma unroll
      for (int m = 0; m < 4; ++m) {
        int row = wco * 64 + m * 16 + l15;
        af[m] = *(const bf16x8*)(wring + s * 8192 + row * 64 + ((kg ^ ((row >> 1) & 3)) << 4));
      }
      #pragma unroll
      for (int r = 0; r < 2; ++r)
        #pragma unroll
        for (int n = 0; n < 4; ++n) {
          int p = (2 * wrow + r + dh) * 66 + n * 16 + l15 + dw;
          bfr[r][n] = *(const bf16x8*)(xcur + p * 64 + ((kg ^ ((p >> 1) & 3)) << 4));
        }

      // 3. stage issues (stay in flight across barriers)
      wstage(g + 2);
      if (tap >= 1 && tap <= 5) xstage((tap - 1) * 8 + wv, ccs, xnxt);

      // 4. raw barrier (no drain)
      __builtin_amdgcn_s_barrier();

      // 5. MFMA cluster
      __builtin_amdgcn_s_setprio(1);
      #pragma unroll
      for (int m = 0; m < 4; ++m)
        #pragma unroll
        for (int r = 0; r < 2; ++r)
          #pragma unroll
          for (int n = 0; n < 4; ++n)
            acc[m][r][n] = __builtin_amdgcn_mfma_f32_16x16x32_bf16(af[m], bfr[r][n], acc[m][r][n], 0, 0, 0);
      __builtin_amdgcn_s_setprio(0);
    }
  }

  // epilogue: out[b][co][h][w] = acc * conv_scale * demod[b][co]
  #pragma unroll
  for (int m = 0; m < 4; ++m) {
    #pragma unroll
    for (int q = 0; q < 4; ++q) {
      int co = co0 + wco * 64 + m * 16 + kg * 4 + q;
      float scl = CONV_SCALE * demod[b * 512 + co];
      #pragma unroll
      for (int r = 0; r < 2; ++r) {
        int h_out = h0 + 2 * wrow + r;
        #pragma unroll
        for (int n = 0; n < 4; ++n) {
          out[(((size_t)(b * 512 + co)) * 64 + h_out) * 64 + n * 16 + l15] = acc[m][r][n][q] * scl;
        }
      }
    }
  }
}

extern "C" void kernel_launch(void* const* d_in, const int* in_sizes, int n_in,
                              void* d_out, int out_size, void* d_ws, size_t ws_size,
                              hipStream_t stream) {
  const float* x      = (const float*)d_in[0];  // (8,512,64,64)
  const float* style  = (const float*)d_in[1];  // (8,512)
  const float* weight = (const float*)d_in[2];  // (1,512,512,3,3)
  const float* mod_w  = (const float*)d_in[3];  // (512,512)
  const float* mod_b  = (const float*)d_in[4];  // (512,)
  float* out = (float*)d_out;

  // workspace layout (~39.4 MB)
  char* ws = (char*)d_ws;
  unsigned short* xT = (unsigned short*)ws;               // 33,554,432 B
  unsigned short* wT = (unsigned short*)(ws + 33554432);  //  4,718,592 B
  float* s     = (float*)(ws + 38273024);                 //     16,384 B
  float* wsq   = (float*)(ws + 38289408);                 //  1,048,576 B
  float* demod = (float*)(ws + 39337984);                 //     16,384 B

  static int lds_set = 0;
  if (!lds_set) {
    (void)hipFuncSetAttribute((const void*)k_conv,
                              hipFuncAttributeMaxDynamicSharedMemorySize, 118272);
    lds_set = 1;
  }

  hipLaunchKernelGGL(k_modulate, dim3(32),       dim3(256), 0, stream, style, mod_w, mod_b, s);
  hipLaunchKernelGGL(k_wTq,      dim3(512),      dim3(256), 0, stream, weight, wT, wsq);
  hipLaunchKernelGGL(k_demod,    dim3(8),        dim3(512), 0, stream, wsq, s, demod);
  hipLaunchKernelGGL(k_xT,       dim3(4, 64, 8), dim3(256), 0, stream, x, s, xT);
  hipLaunchKernelGGL(k_conv,     dim3(256),      dim3(512), 118272, stream, xT, wT, demod, out);
}